// Round 15
// baseline (1357.014 us; speedup 1.0000x reference)
//
#include <hip/hip_runtime.h>

typedef _Float16 half_t;
typedef __attribute__((ext_vector_type(2))) _Float16 half2_t;

__device__ __forceinline__ half2_t bc2(unsigned int u){ return __builtin_bit_cast(half2_t, u); }
__device__ __forceinline__ int   bcI(half2_t v){ return __builtin_bit_cast(int, v); }
__device__ __forceinline__ half2_t bcH(int v){ return __builtin_bit_cast(half2_t, v); }
__device__ __forceinline__ float fdot2f(half2_t a, half2_t b, float c){
  return __builtin_amdgcn_fdot2(a, b, c, false);
}
__device__ __forceinline__ float rcp_f(float x){ return __builtin_amdgcn_rcpf(x); }
__device__ __forceinline__ float sigmoidf_(float x){ return rcp_f(1.0f+__expf(-x)); }
__device__ __forceinline__ float tanhf_(float x){ return 1.0f - 2.0f*rcp_f(__expf(2.0f*x)+1.0f); }

// DPP quad_perm cross-lane (VALU pipe): xor1 = 0xB1, xor2 = 0x4E
__device__ __forceinline__ float qxor1(float v){
  return __builtin_bit_cast(float, __builtin_amdgcn_mov_dpp(__builtin_bit_cast(int,v),0xB1,0xF,0xF,true));
}
__device__ __forceinline__ float qxor2(float v){
  return __builtin_bit_cast(float, __builtin_amdgcn_mov_dpp(__builtin_bit_cast(int,v),0x4E,0xF,0xF,true));
}
__device__ __forceinline__ float qsum4(float v){ v += qxor1(v); v += qxor2(v); return v; }

// Barrier WITHOUT vmcnt drain (LDS ordering only; global prefetches stay in flight)
__device__ __forceinline__ void bar(){
  asm volatile("s_waitcnt lgkmcnt(0)\n\ts_barrier" ::: "memory");
}

// 32-half dot: 4 w uint4 vs 4 x uint4 (16 fdot2, 4 chains)
__device__ __forceinline__ float dot32(const uint4* w, const uint4* x){
  float a=0.f,b=0.f,c=0.f,d=0.f;
  #pragma unroll
  for (int m=0;m<4;++m){
    a=fdot2f(bc2(w[m].x),bc2(x[m].x),a);
    b=fdot2f(bc2(w[m].y),bc2(x[m].y),b);
    c=fdot2f(bc2(w[m].z),bc2(x[m].z),c);
    d=fdot2f(bc2(w[m].w),bc2(x[m].w),d);
  }
  return (a+b)+(c+d);
}

// 8 tanh-terms of one uint4 trio into two accumulators
__device__ __forceinline__ void terms8(uint4 hw, uint4 sw, uint4 vv, float& s0, float& s1){
  half2_t h2,s2,v2;
  h2=bc2(hw.x); s2=bc2(sw.x); v2=bc2(vv.x);
  s0 += tanhf_((float)s2[0]+(float)h2[0])*(float)v2[0];
  s1 += tanhf_((float)s2[1]+(float)h2[1])*(float)v2[1];
  h2=bc2(hw.y); s2=bc2(sw.y); v2=bc2(vv.y);
  s0 += tanhf_((float)s2[0]+(float)h2[0])*(float)v2[0];
  s1 += tanhf_((float)s2[1]+(float)h2[1])*(float)v2[1];
  h2=bc2(hw.z); s2=bc2(sw.z); v2=bc2(vv.z);
  s0 += tanhf_((float)s2[0]+(float)h2[0])*(float)v2[0];
  s1 += tanhf_((float)s2[1]+(float)h2[1])*(float)v2[1];
  h2=bc2(hw.w); s2=bc2(sw.w); v2=bc2(vv.w);
  s0 += tanhf_((float)s2[0]+(float)h2[0])*(float)v2[0];
  s1 += tanhf_((float)s2[1]+(float)h2[1])*(float)v2[1];
}

// P6 logits with L lanes per (l,t) pair. L=2: t<=127, L=4: t<=63, L=8: t<=31.
template<int L>
__device__ __forceinline__ void phase6(int i, int tid,
    const half_t* shWh, const half_t* sWs0, const half_t* sWs1,
    const half_t* vw, float* probs0, float* probs1)
{
  const int sub = tid & (L-1);
  const int pid = tid / L;
  const int t6  = (L==2) ? (pid & 127) : (L==4) ? (pid & 63) : (pid & 31);
  const int l6  = (L==2) ? (pid >> 7)  : (L==4) ? (pid >> 6) : (pid >> 5);
  if (t6 <= i){
    const half_t* hwrow = shWh + (size_t)l6*(128*136) + t6*136;
    const half_t* swrow = l6 ? sWs1 : sWs0;
    constexpr int M  = 16/L;
    const int m0 = M*sub;
    const int key = t6 & 15;
    uint4 swr[M], vvr[M];
    #pragma unroll
    for (int mm=0; mm<M; ++mm){
      swr[mm] = *reinterpret_cast<const uint4*>(swrow + 8*(m0+mm));
      vvr[mm] = *reinterpret_cast<const uint4*>(vw + 8*(m0+mm));
    }
    float s0 = 0.f, s1 = 0.f;
    #pragma unroll
    for (int mm=0; mm<M; ++mm){
      int m = m0+mm;
      uint4 hw = *reinterpret_cast<const uint4*>(hwrow + ((m^key)*8));
      terms8(hw, swr[mm], vvr[mm], s0, s1);
    }
    float s = s0 + s1;
    s += qxor1(s);
    if (L>=4) s += qxor2(s);
    if (L>=8) s += __shfl_xor(s,4);
    if (sub==0) (l6 ? probs1 : probs0)[t6] = __expf(s - 4.0f);
  }
}

// Pack f32 matrix (R x K slice at coloff, row stride ld) -> f16 [K/8][RT][8] at row_off.
__global__ void pack_k(const float* __restrict__ src, half_t* __restrict__ dst,
                       int R, int K, int ld, int coloff, int RT, int row_off){
  int idx = blockIdx.x*blockDim.x + threadIdx.x;
  if (idx >= R*K) return;
  int r = idx / K, k = idx - r*K;
  int kc = k >> 3, j = k & 7;
  dst[((size_t)kc*RT + row_off + r)*8 + j] = (half_t)src[(size_t)r*ld + coloff + k];
}

__launch_bounds__(512)
__global__ void gru_main(
    const float* __restrict__ received,
    const float* __restrict__ Wih0d0, const float* __restrict__ Wih0d1,
    const float* __restrict__ bx0d0, const float* __restrict__ bh0d0,
    const float* __restrict__ bx1d0, const float* __restrict__ bh1d0,
    const float* __restrict__ bx0d1, const float* __restrict__ bh0d1,
    const float* __restrict__ bx1d1, const float* __restrict__ bh1d1,
    const float* __restrict__ vW, const float* __restrict__ fc2b,
    const half_t* __restrict__ W0pack, const half_t* __restrict__ W1pack,
    const half_t* __restrict__ WsPack, const half_t* __restrict__ WhPack,
    const half_t* __restrict__ fc2Pack,
    half_t* __restrict__ o1h, half_t* __restrict__ o2h)
{
  const int dec = blockIdx.x >> 5;
  const int b   = blockIdx.x & 31;
  const int tid = threadIdx.x;
  const int q   = tid & 3;     // quad k-slice lane (32 halves each)
  const int r   = tid >> 2;    // 0..127 row id

  const float* bx0  = dec ? bx0d1 : bx0d0;
  const float* bh0  = dec ? bh0d1 : bh0d0;
  const float* bx1  = dec ? bx1d1 : bx1d0;
  const float* bh1  = dec ? bh1d1 : bh1d0;
  const float* Wih0 = dec ? Wih0d1 : Wih0d0;
  const half_t* W0  = W0pack + (size_t)dec*49152;   // [16][384][8]  Whh0
  const half_t* W1  = W1pack + (size_t)dec*98304;   // [16][768][8]  rows 0-383 Wih1, 384-767 Whh1
  half_t* od = dec ? o2h : o1h;

  // rows padded to 136 halves; octet-swizzled by (t&15)
  __shared__ __align__(16) half_t sh_hist[2][128*136];    // raw h history
  __shared__ __align__(16) half_t sh_histWh[2][128*136];  // Wh @ h_raw[t]
  __shared__ __align__(16) half_t sh_sWs16[2][128];
  __shared__ __align__(16) float  sh_probs[2][128];       // unnormalized exp(logit-4)
  __shared__ __align__(16) float  sh_hatt32[2][128];
  __shared__ __align__(16) half_t sh_hatt_pk[2][128];
  __shared__ __align__(16) half_t sh_hraw_pk[2][128];
  __shared__ __align__(16) half_t sh_fc2in[2][256];       // [c | h_raw]
  __shared__ __align__(16) half_t sh_vW16[128];
  __shared__ __align__(16) float4 sh_Wx4[384];            // Wih0 3 cols + bias

  // ---- persistent per-thread biases (all 3 gates of row r) ----
  const float bA0=bh0[r], bA1=bh0[r+128], bA2=bh0[r+256];
  const float bB0=bh1[r], bB1=bh1[r+128], bB2=bh1[r+256];
  const float bC0=bx1[r], bC1=bx1[r+128], bC2=bx1[r+256];
  const float bF = fc2b[r];

  // ---- cross-phase prefetch registers ----
  uint4 wP1[12];   // Whh0 batch, consumed at P1 head
  uint4 wP3[12];   // Wih1 batch, consumed at P3
  uint4 wP5[8];    // Ws/Wh batch, consumed at P3 (h0 dots) and P5 (h1 dots)

  // ---- LDS init + initial wP1 prefetch ----
  {
    uint4 z = make_uint4(0u,0u,0u,0u);
    uint4* ph = reinterpret_cast<uint4*>(&sh_hist[0][0]);     // 4352 u4 each
    uint4* pw = reinterpret_cast<uint4*>(&sh_histWh[0][0]);
    for (int j=tid; j<4352; j+=512){ ph[j]=z; pw[j]=z; }
  }
  if (tid < 256){ int l=tid>>7, rr=tid&127; sh_hatt32[l][rr]=0.f; sh_hatt_pk[l][rr]=(half_t)0.f; }
  if (tid < 128) sh_vW16[tid] = (half_t)vW[tid];
  if (tid < 384) sh_Wx4[tid] = make_float4(Wih0[tid*3], Wih0[tid*3+1], Wih0[tid*3+2], bx0[tid]);
  #pragma unroll
  for (int n=0;n<3;++n)
    #pragma unroll
    for (int m=0;m<4;++m)
      wP1[4*n+m] = *reinterpret_cast<const uint4*>(W0 + ((size_t)(4*q+m)*384 + r + 128*n)*8);
  bar();

  float g1h0=0.f, g1h1=0.f, g1h2=0.f;   // carried P1 -> P3

  for (int i=0; i<128; ++i){
    const int phys = i*136 + ((r>>3)^(i&15))*8 + (r&7);
    // ==== P1: gh0 (wP1) + g1h (reg-carried) + gx0 inline + layer0 cell ====
    {
      uint4 w1[12];   // W1 rows 384-767, issued at head; latency hides under wP1 dots
      #pragma unroll
      for (int n=0;n<3;++n)
        #pragma unroll
        for (int m=0;m<4;++m)
          w1[4*n+m] = *reinterpret_cast<const uint4*>(W1 + ((size_t)(4*q+m)*768 + 384 + r + 128*n)*8);
      uint4 xa[4];
      #pragma unroll
      for (int m=0;m<4;++m) xa[m] = *reinterpret_cast<const uint4*>(&sh_hatt_pk[0][32*q+8*m]);
      float a0 = dot32(&wP1[0],xa), a1 = dot32(&wP1[4],xa), a2 = dot32(&wP1[8],xa);
      uint4 xb[4];
      #pragma unroll
      for (int m=0;m<4;++m) xb[m] = *reinterpret_cast<const uint4*>(&sh_hatt_pk[1][32*q+8*m]);
      float a3 = dot32(&w1[0],xb), a4 = dot32(&w1[4],xb), a5 = dot32(&w1[8],xb);
      __builtin_amdgcn_sched_barrier(0);
      // prefetch P3's Wih1 batch AND the Ws/Wh batch (w1/wP1 dead after dots)
      #pragma unroll
      for (int n=0;n<3;++n)
        #pragma unroll
        for (int m=0;m<4;++m)
          wP3[4*n+m] = *reinterpret_cast<const uint4*>(W1 + ((size_t)(4*q+m)*768 + r + 128*n)*8);
      #pragma unroll
      for (int m=0;m<4;++m){
        wP5[m]   = *reinterpret_cast<const uint4*>(WsPack + ((size_t)(4*q+m)*128 + r)*8);
        wP5[4+m] = *reinterpret_cast<const uint4*>(WhPack + ((size_t)(4*q+m)*128 + r)*8);
      }
      a0=qsum4(a0)+bA0; a1=qsum4(a1)+bA1; a2=qsum4(a2)+bA2;
      g1h0=qsum4(a3)+bB0; g1h1=qsum4(a4)+bB1; g1h2=qsum4(a5)+bB2;
      // layer0 cell (all 4 lanes redundantly; q==0 writes)
      const float* xr = &received[((size_t)b*128+i)*3];
      float xv0=xr[0], xv1=xr[1], xv2=xr[2];
      float4 wxa=sh_Wx4[r], wxb=sh_Wx4[r+128], wxc=sh_Wx4[r+256];
      float gxr = wxa.w + wxa.x*xv0 + wxa.y*xv1 + wxa.z*xv2;
      float gxz = wxb.w + wxb.x*xv0 + wxb.y*xv1 + wxb.z*xv2;
      float gxn = wxc.w + wxc.x*xv0 + wxc.y*xv1 + wxc.z*xv2;
      float rr = sigmoidf_(gxr + a0);
      float zz = sigmoidf_(gxz + a1);
      float nn = tanhf_(gxn + rr*a2);
      float h0 = (1.f-zz)*nn + zz*sh_hatt32[0][r];
      if (q==0){
        half_t hh=(half_t)h0;
        sh_hist[0][phys]=hh;
        sh_hraw_pk[0][r]=hh; sh_fc2in[0][128+r]=hh;
      }
    }
    bar();
    // ==== P3: g1x (wP3) + layer1 cell + layer0 projections (Ws@h0, Wh@h0 via wP5) ====
    {
      uint4 xc[4];
      #pragma unroll
      for (int m=0;m<4;++m) xc[m] = *reinterpret_cast<const uint4*>(&sh_hraw_pk[0][32*q+8*m]);
      float c0 = dot32(&wP3[0],xc), c1 = dot32(&wP3[4],xc), c2 = dot32(&wP3[8],xc);
      __builtin_amdgcn_sched_barrier(0);
      float s0 = dot32(&wP5[0],xc);    // Ws @ h0
      float hw0 = dot32(&wP5[4],xc);   // Wh @ h0
      c0=qsum4(c0)+bC0; c1=qsum4(c1)+bC1; c2=qsum4(c2)+bC2;
      s0=qsum4(s0); hw0=qsum4(hw0);
      float rr = sigmoidf_(c0 + g1h0);
      float zz = sigmoidf_(c1 + g1h1);
      float nn = tanhf_(c2 + rr*g1h2);
      float h1 = (1.f-zz)*nn + zz*sh_hatt32[1][r];
      if (q==0){
        half_t hh=(half_t)h1;
        sh_hist[1][phys]=hh;
        sh_hraw_pk[1][r]=hh; sh_fc2in[1][128+r]=hh;
        od[(size_t)(b*128+i)*128 + r]=hh;
      } else if (q==1){
        sh_histWh[0][phys]=(half_t)hw0;
      } else if (q==2){
        sh_sWs16[0][r]=(half_t)s0;
      }
    }
    bar();
    // ==== P5: layer1 projections only (Ws@h1, Wh@h1 via wP5) ====
    {
      uint4 xb[4];
      #pragma unroll
      for (int m=0;m<4;++m)
        xb[m] = *reinterpret_cast<const uint4*>(&sh_hraw_pk[1][32*q+8*m]);
      float sA1=qsum4(dot32(&wP5[0],xb));
      float sB1=qsum4(dot32(&wP5[4],xb));
      if      (q==1) sh_sWs16[1][r] = (half_t)sA1;
      else if (q==3) sh_histWh[1][phys] = (half_t)sB1;
    }
    bar();
    if (i > 0){
      // ==== P6: unnormalized probs, variable lane-split by i ====
      if (i < 32)      phase6<8>(i, tid, &sh_histWh[0][0], &sh_sWs16[0][0], &sh_sWs16[1][0], &sh_vW16[0], &sh_probs[0][0], &sh_probs[1][0]);
      else if (i < 64) phase6<4>(i, tid, &sh_histWh[0][0], &sh_sWs16[0][0], &sh_sWs16[1][0], &sh_vW16[0], &sh_probs[0][0], &sh_probs[1][0]);
      else             phase6<2>(i, tid, &sh_histWh[0][0], &sh_sWs16[0][0], &sh_sWs16[1][0], &sh_vW16[0], &sh_probs[0][0], &sh_probs[1][0]);
      if (tid < 256){ int l=tid>>7, t=tid&127; if (t > i) sh_probs[l][t] = 0.f; }
      bar();
      // ==== P8: wE prefetch (for P9) + ctx + Sum(p), kmax-bounded; f16-packed reduce ====
      uint4 wE[8];
      #pragma unroll
      for (int c=0;c<8;++c)
        wE[c] = *reinterpret_cast<const uint4*>(fc2Pack + ((size_t)(8*q+c)*128 + r)*8);
      {
        int ts=tid&15, oc=(tid>>4)&15, l8=tid>>8;
        float c0=0.f,c1=0.f,c2=0.f,c3=0.f,c4=0.f,c5=0.f,c6=0.f,c7=0.f, ps=0.f;
        int kmax = (i>>4)+1;
        for (int k=0;k<kmax;++k){
          int t = ts + 16*k;
          float p = sh_probs[l8][t];
          uint4 hv = *reinterpret_cast<const uint4*>(&sh_hist[l8][t*136 + ((oc^(t&15))*8)]);
          half2_t a=bc2(hv.x), e=bc2(hv.y), f=bc2(hv.z), g=bc2(hv.w);
          c0+=p*(float)a[0]; c1+=p*(float)a[1]; c2+=p*(float)e[0]; c3+=p*(float)e[1];
          c4+=p*(float)f[0]; c5+=p*(float)f[1]; c6+=p*(float)g[0]; c7+=p*(float)g[1];
          ps+=p;
        }
        c0+=qxor1(c0); c0+=qxor2(c0);  c1+=qxor1(c1); c1+=qxor2(c1);
        c2+=qxor1(c2); c2+=qxor2(c2);  c3+=qxor1(c3); c3+=qxor2(c3);
        c4+=qxor1(c4); c4+=qxor2(c4);  c5+=qxor1(c5); c5+=qxor2(c5);
        c6+=qxor1(c6); c6+=qxor2(c6);  c7+=qxor1(c7); c7+=qxor2(c7);
        ps+=qxor1(ps); ps+=qxor2(ps);
        half2_t p01={(half_t)c0,(half_t)c1}, p23={(half_t)c2,(half_t)c3};
        half2_t p45={(half_t)c4,(half_t)c5}, p67={(half_t)c6,(half_t)c7};
        p01 = p01 + bcH(__shfl_xor(bcI(p01),4)); p23 = p23 + bcH(__shfl_xor(bcI(p23),4));
        p45 = p45 + bcH(__shfl_xor(bcI(p45),4)); p67 = p67 + bcH(__shfl_xor(bcI(p67),4));
        ps += __shfl_xor(ps,4);
        p01 = p01 + bcH(__shfl_xor(bcI(p01),8)); p23 = p23 + bcH(__shfl_xor(bcI(p23),8));
        p45 = p45 + bcH(__shfl_xor(bcI(p45),8)); p67 = p67 + bcH(__shfl_xor(bcI(p67),8));
        ps += __shfl_xor(ps,8);
        if (ts==0){
          float inv = rcp_f(ps);
          half2_t o01={(half_t)((float)p01[0]*inv),(half_t)((float)p01[1]*inv)};
          half2_t o23={(half_t)((float)p23[0]*inv),(half_t)((float)p23[1]*inv)};
          half2_t o45={(half_t)((float)p45[0]*inv),(half_t)((float)p45[1]*inv)};
          half2_t o67={(half_t)((float)p67[0]*inv),(half_t)((float)p67[1]*inv)};
          *reinterpret_cast<uint4*>(&sh_fc2in[l8][oc*8]) =
              make_uint4((unsigned)bcI(o01),(unsigned)bcI(o23),(unsigned)bcI(o45),(unsigned)bcI(o67));
        }
      }
      bar();
      // ==== P9: h_att[l] = fc2 @ [c|h_raw] + fc2_b (wE preloaded in P8) ====
      {
        float e0=0.f, e1=0.f;
        #pragma unroll
        for (int h=0; h<2; ++h){
          uint4 x0[4], x1[4];
          #pragma unroll
          for (int m=0;m<4;++m){
            x0[m] = *reinterpret_cast<const uint4*>(&sh_fc2in[0][64*q + 32*h + 8*m]);
            x1[m] = *reinterpret_cast<const uint4*>(&sh_fc2in[1][64*q + 32*h + 8*m]);
          }
          e0 += dot32(&wE[4*h],x0);
          e1 += dot32(&wE[4*h],x1);
        }
        e0 = qsum4(e0); e1 = qsum4(e1);
        __builtin_amdgcn_sched_barrier(0);
        // prefetch next step's Whh0 batch (everything else dead)
        #pragma unroll
        for (int n=0;n<3;++n)
          #pragma unroll
          for (int m=0;m<4;++m)
            wP1[4*n+m] = *reinterpret_cast<const uint4*>(W0 + ((size_t)(4*q+m)*384 + r + 128*n)*8);
        if      (q==0){ float v=e0+bF; sh_hatt32[0][r]=v; sh_hatt_pk[0][r]=(half_t)v; }
        else if (q==1){ float v=e1+bF; sh_hatt32[1][r]=v; sh_hatt_pk[1][r]=(half_t)v; }
      }
    } else {
      // prefetch next step's Whh0 batch
      #pragma unroll
      for (int n=0;n<3;++n)
        #pragma unroll
        for (int m=0;m<4;++m)
          wP1[4*n+m] = *reinterpret_cast<const uint4*>(W0 + ((size_t)(4*q+m)*384 + r + 128*n)*8);
      if (tid < 256){
        int l=tid>>7, row=tid&127;
        float hv = (float)sh_hraw_pk[l][row];
        sh_hatt32[l][row]=hv; sh_hatt_pk[l][row]=(half_t)hv;
      }
    }
    bar();
  }
}

// Final: out[b,t] = sigmoid(tanh(out_W . [o1[b,t] | o2[b,min(t+10,127)]] + out_b))
__global__ void out_kernel(const half_t* __restrict__ o1h, const half_t* __restrict__ o2h,
                           const float* __restrict__ outW, const float* __restrict__ outb,
                           float* __restrict__ dout){
  int tid = blockIdx.x*blockDim.x + threadIdx.x;
  int q = tid&3, job = tid>>2;
  int b = job>>7, t = job&127;
  int t2 = t+10; if (t2>127) t2=127;
  const half_t* r1 = o1h + (size_t)(b*128+t)*128;
  const half_t* r2 = o2h + (size_t)(b*128+t2)*128;
  float acc=0.f;
  for (int j=q*32; j<q*32+32; ++j) acc += outW[j]*(float)r1[j];
  for (int j=q*32; j<q*32+32; ++j) acc += outW[128+j]*(float)r2[j];
  acc += __shfl_xor(acc,1);
  acc += __shfl_xor(acc,2);
  if (q==0){
    float d = tanhf_(acc + outb[0]);
    dout[job] = rcp_f(1.f+__expf(-d));
  }
}

static inline void launch_pack(const void* src, half_t* dst, int R, int K, int ld,
                               int coloff, int RT, int row_off, hipStream_t s){
  int total = R*K;
  pack_k<<<(total+255)/256, 256, 0, s>>>((const float*)src, dst, R, K, ld, coloff, RT, row_off);
}

extern "C" void kernel_launch(void* const* d_in, const int* in_sizes, int n_in,
                              void* d_out, int out_size, void* d_ws, size_t ws_size,
                              hipStream_t stream) {
  const float* received = (const float*)d_in[0];
  const float* Wih1_0 = (const float*)d_in[1];
  const float* Whh1_0 = (const float*)d_in[2];
  const float* bih1_0 = (const float*)d_in[3];
  const float* bhh1_0 = (const float*)d_in[4];
  const float* Wih1_1 = (const float*)d_in[5];
  const float* Whh1_1 = (const float*)d_in[6];
  const float* bih1_1 = (const float*)d_in[7];
  const float* bhh1_1 = (const float*)d_in[8];
  const float* Wih2_0 = (const float*)d_in[9];
  const float* Whh2_0 = (const float*)d_in[10];
  const float* bih2_0 = (const float*)d_in[11];
  const float* bhh2_0 = (const float*)d_in[12];
  const float* Wih2_1 = (const float*)d_in[13];
  const float* Whh2_1 = (const float*)d_in[14];
  const float* bih2_1 = (const float*)d_in[15];
  const float* bhh2_1 = (const float*)d_in[16];
  const float* attn_W = (const float*)d_in[17];
  const float* v_W    = (const float*)d_in[18];
  const float* fc2_W  = (const float*)d_in[19];
  const float* fc2_b  = (const float*)d_in[20];
  const float* out_W  = (const float*)d_in[21];
  const float* out_b  = (const float*)d_in[22];

  half_t* ws = (half_t*)d_ws;
  half_t* W0pack  = ws + 0;        // 2 x [16][384][8] = 98304
  half_t* W1pack  = ws + 98304;    // 2 x [16][768][8] = 196608
  half_t* WsPack  = ws + 294912;   // [16][128][8] = 16384
  half_t* WhPack  = ws + 311296;   // 16384
  half_t* fc2Pack = ws + 327552;   // [32][128][8] = 32768
  half_t* o1h     = ws + 360448;   // 32*128*128 = 524288
  half_t* o2h     = ws + 884736;   // 524288

  launch_pack(Whh1_0, W0pack,          384, 128, 128, 0, 384, 0, stream);
  launch_pack(Whh2_0, W0pack + 49152,  384, 128, 128, 0, 384, 0, stream);
  launch_pack(Wih1_1, W1pack,          384, 128, 128, 0, 768, 0, stream);
  launch_pack(Whh1_1, W1pack,          384, 128, 128, 0, 768, 384, stream);
  launch_pack(Wih2_1, W1pack + 98304,  384, 128, 128, 0, 768, 0, stream);
  launch_pack(Whh2_1, W1pack + 98304,  384, 128, 128, 0, 768, 384, stream);
  launch_pack(attn_W, WsPack,          128, 128, 256, 0,   128, 0, stream);
  launch_pack(attn_W, WhPack,          128, 128, 256, 128, 128, 0, stream);
  launch_pack(fc2_W,  fc2Pack,         128, 256, 256, 0,   128, 0, stream);

  gru_main<<<64, 512, 0, stream>>>(
      received,
      Wih1_0, Wih2_0,
      bih1_0, bhh1_0, bih1_1, bhh1_1,
      bih2_0, bhh2_0, bih2_1, bhh2_1,
      v_W, fc2_b,
      W0pack, W1pack, WsPack, WhPack, fc2Pack,
      o1h, o2h);

  out_kernel<<<64, 256, 0, stream>>>(o1h, o2h, out_W, out_b, (float*)d_out);
}

// Round 16
// 1288.046 us; speedup vs baseline: 1.0535x; 1.0535x over previous
//
#include <hip/hip_runtime.h>

typedef _Float16 half_t;
typedef __attribute__((ext_vector_type(2))) _Float16 half2_t;

__device__ __forceinline__ half2_t bc2(unsigned int u){ return __builtin_bit_cast(half2_t, u); }
__device__ __forceinline__ int   bcI(half2_t v){ return __builtin_bit_cast(int, v); }
__device__ __forceinline__ half2_t bcH(int v){ return __builtin_bit_cast(half2_t, v); }
__device__ __forceinline__ float fdot2f(half2_t a, half2_t b, float c){
  return __builtin_amdgcn_fdot2(a, b, c, false);
}
__device__ __forceinline__ float rcp_f(float x){ return __builtin_amdgcn_rcpf(x); }
__device__ __forceinline__ float sigmoidf_(float x){ return rcp_f(1.0f+__expf(-x)); }
__device__ __forceinline__ float tanhf_(float x){ return 1.0f - 2.0f*rcp_f(__expf(2.0f*x)+1.0f); }

// DPP quad_perm cross-lane (VALU pipe): xor1 = 0xB1, xor2 = 0x4E
__device__ __forceinline__ float qxor1(float v){
  return __builtin_bit_cast(float, __builtin_amdgcn_mov_dpp(__builtin_bit_cast(int,v),0xB1,0xF,0xF,true));
}
__device__ __forceinline__ float qxor2(float v){
  return __builtin_bit_cast(float, __builtin_amdgcn_mov_dpp(__builtin_bit_cast(int,v),0x4E,0xF,0xF,true));
}
__device__ __forceinline__ float qsum4(float v){ v += qxor1(v); v += qxor2(v); return v; }

// Barrier WITHOUT vmcnt drain (LDS ordering only; global prefetches stay in flight)
__device__ __forceinline__ void bar(){
  asm volatile("s_waitcnt lgkmcnt(0)\n\ts_barrier" ::: "memory");
}

// 32-half dot: 4 w uint4 vs 4 x uint4 (16 fdot2, 4 chains)
__device__ __forceinline__ float dot32(const uint4* w, const uint4* x){
  float a=0.f,b=0.f,c=0.f,d=0.f;
  #pragma unroll
  for (int m=0;m<4;++m){
    a=fdot2f(bc2(w[m].x),bc2(x[m].x),a);
    b=fdot2f(bc2(w[m].y),bc2(x[m].y),b);
    c=fdot2f(bc2(w[m].z),bc2(x[m].z),c);
    d=fdot2f(bc2(w[m].w),bc2(x[m].w),d);
  }
  return (a+b)+(c+d);
}

// 8 tanh-terms of one uint4 trio into two accumulators
__device__ __forceinline__ void terms8(uint4 hw, uint4 sw, uint4 vv, float& s0, float& s1){
  half2_t h2,s2,v2;
  h2=bc2(hw.x); s2=bc2(sw.x); v2=bc2(vv.x);
  s0 += tanhf_((float)s2[0]+(float)h2[0])*(float)v2[0];
  s1 += tanhf_((float)s2[1]+(float)h2[1])*(float)v2[1];
  h2=bc2(hw.y); s2=bc2(sw.y); v2=bc2(vv.y);
  s0 += tanhf_((float)s2[0]+(float)h2[0])*(float)v2[0];
  s1 += tanhf_((float)s2[1]+(float)h2[1])*(float)v2[1];
  h2=bc2(hw.z); s2=bc2(sw.z); v2=bc2(vv.z);
  s0 += tanhf_((float)s2[0]+(float)h2[0])*(float)v2[0];
  s1 += tanhf_((float)s2[1]+(float)h2[1])*(float)v2[1];
  h2=bc2(hw.w); s2=bc2(sw.w); v2=bc2(vv.w);
  s0 += tanhf_((float)s2[0]+(float)h2[0])*(float)v2[0];
  s1 += tanhf_((float)s2[1]+(float)h2[1])*(float)v2[1];
}

// P6 logits with L lanes per (l,t) pair. L=2: t<=127, L=4: t<=63, L=8: t<=31.
template<int L>
__device__ __forceinline__ void phase6(int i, int tid,
    const half_t* shWh, const half_t* sWs0, const half_t* sWs1,
    const half_t* vw, float* probs0, float* probs1)
{
  const int sub = tid & (L-1);
  const int pid = tid / L;
  const int t6  = (L==2) ? (pid & 127) : (L==4) ? (pid & 63) : (pid & 31);
  const int l6  = (L==2) ? (pid >> 7)  : (L==4) ? (pid >> 6) : (pid >> 5);
  if (t6 <= i){
    const half_t* hwrow = shWh + (size_t)l6*(128*136) + t6*136;
    const half_t* swrow = l6 ? sWs1 : sWs0;
    constexpr int M  = 16/L;
    const int m0 = M*sub;
    const int key = t6 & 15;
    // hoist broadcast sw/vv loads out of the tanh loop
    uint4 swr[M], vvr[M];
    #pragma unroll
    for (int mm=0; mm<M; ++mm){
      swr[mm] = *reinterpret_cast<const uint4*>(swrow + 8*(m0+mm));
      vvr[mm] = *reinterpret_cast<const uint4*>(vw + 8*(m0+mm));
    }
    float s0 = 0.f, s1 = 0.f;
    #pragma unroll
    for (int mm=0; mm<M; ++mm){
      int m = m0+mm;
      uint4 hw = *reinterpret_cast<const uint4*>(hwrow + ((m^key)*8));
      terms8(hw, swr[mm], vvr[mm], s0, s1);
    }
    float s = s0 + s1;
    s += qxor1(s);
    if (L>=4) s += qxor2(s);
    if (L>=8) s += __shfl_xor(s,4);
    if (sub==0) (l6 ? probs1 : probs0)[t6] = __expf(s - 4.0f);
  }
}

// Pack f32 matrix (R x K slice at coloff, row stride ld) -> f16 [K/8][RT][8] at row_off.
__global__ void pack_k(const float* __restrict__ src, half_t* __restrict__ dst,
                       int R, int K, int ld, int coloff, int RT, int row_off){
  int idx = blockIdx.x*blockDim.x + threadIdx.x;
  if (idx >= R*K) return;
  int r = idx / K, k = idx - r*K;
  int kc = k >> 3, j = k & 7;
  dst[((size_t)kc*RT + row_off + r)*8 + j] = (half_t)src[(size_t)r*ld + coloff + k];
}

__launch_bounds__(512)
__global__ void gru_main(
    const float* __restrict__ received,
    const float* __restrict__ Wih0d0, const float* __restrict__ Wih0d1,
    const float* __restrict__ bx0d0, const float* __restrict__ bh0d0,
    const float* __restrict__ bx1d0, const float* __restrict__ bh1d0,
    const float* __restrict__ bx0d1, const float* __restrict__ bh0d1,
    const float* __restrict__ bx1d1, const float* __restrict__ bh1d1,
    const float* __restrict__ vW, const float* __restrict__ fc2b,
    const half_t* __restrict__ W0pack, const half_t* __restrict__ W1pack,
    const half_t* __restrict__ WsPack, const half_t* __restrict__ WhPack,
    const half_t* __restrict__ fc2Pack,
    half_t* __restrict__ o1h, half_t* __restrict__ o2h)
{
  const int dec = blockIdx.x >> 5;
  const int b   = blockIdx.x & 31;
  const int tid = threadIdx.x;
  const int q   = tid & 3;     // quad k-slice lane (32 halves each)
  const int r   = tid >> 2;    // 0..127 row id

  const float* bx0  = dec ? bx0d1 : bx0d0;
  const float* bh0  = dec ? bh0d1 : bh0d0;
  const float* bx1  = dec ? bx1d1 : bx1d0;
  const float* bh1  = dec ? bh1d1 : bh1d0;
  const float* Wih0 = dec ? Wih0d1 : Wih0d0;
  const half_t* W0  = W0pack + (size_t)dec*49152;   // [16][384][8]  Whh0
  const half_t* W1  = W1pack + (size_t)dec*98304;   // [16][768][8]  rows 0-383 Wih1, 384-767 Whh1
  half_t* od = dec ? o2h : o1h;

  // rows padded to 136 halves; octet-swizzled by (t&15)
  __shared__ __align__(16) half_t sh_hist[2][128*136];    // raw h history
  __shared__ __align__(16) half_t sh_histWh[2][128*136];  // Wh @ h_raw[t]
  __shared__ __align__(16) half_t sh_sWs16[2][128];
  __shared__ __align__(16) float  sh_probs[2][128];       // unnormalized exp(logit-4)
  __shared__ __align__(16) float  sh_hatt32[2][128];
  __shared__ __align__(16) half_t sh_hatt_pk[2][128];
  __shared__ __align__(16) float  sh_hraw32[2][128];
  __shared__ __align__(16) half_t sh_hraw_pk[2][128];
  __shared__ __align__(16) half_t sh_fc2in[2][256];       // [c | h_raw]
  __shared__ __align__(16) half_t sh_vW16[128];
  __shared__ __align__(16) float4 sh_Wx4[384];            // Wih0 3 cols + bias

  // ---- persistent per-thread biases (all 3 gates of row r) ----
  const float bA0=bh0[r], bA1=bh0[r+128], bA2=bh0[r+256];
  const float bB0=bh1[r], bB1=bh1[r+128], bB2=bh1[r+256];
  const float bC0=bx1[r], bC1=bx1[r+128], bC2=bx1[r+256];
  const float bF = fc2b[r];

  // ---- cross-phase prefetch registers ----
  uint4 wP1[12];   // Whh0 batch, consumed at P1 head
  uint4 wP3[12];   // Wih1 batch, consumed at P3
  uint4 wP5[8];    // Ws/Wh batch, consumed at P5

  // ---- LDS init + initial wP1 prefetch ----
  {
    uint4 z = make_uint4(0u,0u,0u,0u);
    uint4* ph = reinterpret_cast<uint4*>(&sh_hist[0][0]);     // 4352 u4 each
    uint4* pw = reinterpret_cast<uint4*>(&sh_histWh[0][0]);
    for (int j=tid; j<4352; j+=512){ ph[j]=z; pw[j]=z; }
  }
  if (tid < 256){ int l=tid>>7, rr=tid&127; sh_hatt32[l][rr]=0.f; sh_hatt_pk[l][rr]=(half_t)0.f; }
  if (tid < 128) sh_vW16[tid] = (half_t)vW[tid];
  if (tid < 384) sh_Wx4[tid] = make_float4(Wih0[tid*3], Wih0[tid*3+1], Wih0[tid*3+2], bx0[tid]);
  #pragma unroll
  for (int n=0;n<3;++n)
    #pragma unroll
    for (int m=0;m<4;++m)
      wP1[4*n+m] = *reinterpret_cast<const uint4*>(W0 + ((size_t)(4*q+m)*384 + r + 128*n)*8);
  bar();

  float g1h0=0.f, g1h1=0.f, g1h2=0.f;   // carried P1 -> P3

  for (int i=0; i<128; ++i){
    const int phys = i*136 + ((r>>3)^(i&15))*8 + (r&7);
    // ==== P1: gh0 (wP1) + g1h (reg-carried) + gx0 inline + layer0 cell ====
    {
      uint4 w1[12];   // W1 rows 384-767, issued at head; latency hides under wP1 dots
      #pragma unroll
      for (int n=0;n<3;++n)
        #pragma unroll
        for (int m=0;m<4;++m)
          w1[4*n+m] = *reinterpret_cast<const uint4*>(W1 + ((size_t)(4*q+m)*768 + 384 + r + 128*n)*8);
      uint4 xa[4];
      #pragma unroll
      for (int m=0;m<4;++m) xa[m] = *reinterpret_cast<const uint4*>(&sh_hatt_pk[0][32*q+8*m]);
      float a0 = dot32(&wP1[0],xa), a1 = dot32(&wP1[4],xa), a2 = dot32(&wP1[8],xa);
      uint4 xb[4];
      #pragma unroll
      for (int m=0;m<4;++m) xb[m] = *reinterpret_cast<const uint4*>(&sh_hatt_pk[1][32*q+8*m]);
      float a3 = dot32(&w1[0],xb), a4 = dot32(&w1[4],xb), a5 = dot32(&w1[8],xb);
      __builtin_amdgcn_sched_barrier(0);
      // prefetch P3's Wih1 batch (w1/wP1 dead after dots)
      #pragma unroll
      for (int n=0;n<3;++n)
        #pragma unroll
        for (int m=0;m<4;++m)
          wP3[4*n+m] = *reinterpret_cast<const uint4*>(W1 + ((size_t)(4*q+m)*768 + r + 128*n)*8);
      a0=qsum4(a0)+bA0; a1=qsum4(a1)+bA1; a2=qsum4(a2)+bA2;
      g1h0=qsum4(a3)+bB0; g1h1=qsum4(a4)+bB1; g1h2=qsum4(a5)+bB2;
      // layer0 cell (all 4 lanes redundantly; q==0 writes)
      const float* xr = &received[((size_t)b*128+i)*3];
      float xv0=xr[0], xv1=xr[1], xv2=xr[2];
      float4 wxa=sh_Wx4[r], wxb=sh_Wx4[r+128], wxc=sh_Wx4[r+256];
      float gxr = wxa.w + wxa.x*xv0 + wxa.y*xv1 + wxa.z*xv2;
      float gxz = wxb.w + wxb.x*xv0 + wxb.y*xv1 + wxb.z*xv2;
      float gxn = wxc.w + wxc.x*xv0 + wxc.y*xv1 + wxc.z*xv2;
      float rr = sigmoidf_(gxr + a0);
      float zz = sigmoidf_(gxz + a1);
      float nn = tanhf_(gxn + rr*a2);
      float h0 = (1.f-zz)*nn + zz*sh_hatt32[0][r];
      if (q==0){
        sh_hraw32[0][r]=h0;
        half_t hh=(half_t)h0;
        sh_hist[0][phys]=hh;
        sh_hraw_pk[0][r]=hh; sh_fc2in[0][128+r]=hh;
      }
    }
    bar();
    // ==== P3: g1x (wP3) + layer1 cell (g1h reg-carried) ====
    {
      uint4 xc[4];
      #pragma unroll
      for (int m=0;m<4;++m) xc[m] = *reinterpret_cast<const uint4*>(&sh_hraw_pk[0][32*q+8*m]);
      float c0 = dot32(&wP3[0],xc), c1 = dot32(&wP3[4],xc), c2 = dot32(&wP3[8],xc);
      __builtin_amdgcn_sched_barrier(0);
      // prefetch P5's Ws/Wh batch
      #pragma unroll
      for (int m=0;m<4;++m){
        wP5[m]   = *reinterpret_cast<const uint4*>(WsPack + ((size_t)(4*q+m)*128 + r)*8);
        wP5[4+m] = *reinterpret_cast<const uint4*>(WhPack + ((size_t)(4*q+m)*128 + r)*8);
      }
      c0=qsum4(c0)+bC0; c1=qsum4(c1)+bC1; c2=qsum4(c2)+bC2;
      float rr = sigmoidf_(c0 + g1h0);
      float zz = sigmoidf_(c1 + g1h1);
      float nn = tanhf_(c2 + rr*g1h2);
      float h1 = (1.f-zz)*nn + zz*sh_hatt32[1][r];
      if (q==0){
        sh_hraw32[1][r]=h1;
        half_t hh=(half_t)h1;
        sh_hist[1][phys]=hh;
        sh_hraw_pk[1][r]=hh; sh_fc2in[1][128+r]=hh;
        od[(size_t)(b*128+i)*128 + r]=hh;
      }
    }
    bar();
    // ==== P5: sWs[l]=Ws@h_raw[l] (f16), histWh[l][i]=Wh@h_raw[l] (wP5 prefetched) ====
    {
      uint4 xa[4], xb[4];
      #pragma unroll
      for (int m=0;m<4;++m){
        xa[m] = *reinterpret_cast<const uint4*>(&sh_hraw_pk[0][32*q+8*m]);
        xb[m] = *reinterpret_cast<const uint4*>(&sh_hraw_pk[1][32*q+8*m]);
      }
      float sA0=qsum4(dot32(&wP5[0],xa));
      float sA1=qsum4(dot32(&wP5[0],xb));
      float sB0=qsum4(dot32(&wP5[4],xa));
      float sB1=qsum4(dot32(&wP5[4],xb));
      if      (q==0) sh_sWs16[0][r] = (half_t)sA0;
      else if (q==1) sh_sWs16[1][r] = (half_t)sA1;
      else if (q==2) sh_histWh[0][phys] = (half_t)sB0;
      else           sh_histWh[1][phys] = (half_t)sB1;
    }
    bar();
    if (i > 0){
      // ==== P6: unnormalized probs, variable lane-split by i ====
      if (i < 32)      phase6<8>(i, tid, &sh_histWh[0][0], &sh_sWs16[0][0], &sh_sWs16[1][0], &sh_vW16[0], &sh_probs[0][0], &sh_probs[1][0]);
      else if (i < 64) phase6<4>(i, tid, &sh_histWh[0][0], &sh_sWs16[0][0], &sh_sWs16[1][0], &sh_vW16[0], &sh_probs[0][0], &sh_probs[1][0]);
      else             phase6<2>(i, tid, &sh_histWh[0][0], &sh_sWs16[0][0], &sh_sWs16[1][0], &sh_vW16[0], &sh_probs[0][0], &sh_probs[1][0]);
      if (tid < 256){ int l=tid>>7, t=tid&127; if (t > i) sh_probs[l][t] = 0.f; }
      bar();
      // ==== P8: wE prefetch (for P9) + ctx + Sum(p), kmax-bounded; f16-packed reduce ====
      uint4 wE[8];
      #pragma unroll
      for (int c=0;c<8;++c)
        wE[c] = *reinterpret_cast<const uint4*>(fc2Pack + ((size_t)(8*q+c)*128 + r)*8);
      {
        int ts=tid&15, oc=(tid>>4)&15, l8=tid>>8;
        float c0=0.f,c1=0.f,c2=0.f,c3=0.f,c4=0.f,c5=0.f,c6=0.f,c7=0.f, ps=0.f;
        int kmax = (i>>4)+1;
        for (int k=0;k<kmax;++k){
          int t = ts + 16*k;
          float p = sh_probs[l8][t];
          uint4 hv = *reinterpret_cast<const uint4*>(&sh_hist[l8][t*136 + ((oc^(t&15))*8)]);
          half2_t a=bc2(hv.x), e=bc2(hv.y), f=bc2(hv.z), g=bc2(hv.w);
          c0+=p*(float)a[0]; c1+=p*(float)a[1]; c2+=p*(float)e[0]; c3+=p*(float)e[1];
          c4+=p*(float)f[0]; c5+=p*(float)f[1]; c6+=p*(float)g[0]; c7+=p*(float)g[1];
          ps+=p;
        }
        c0+=qxor1(c0); c0+=qxor2(c0);  c1+=qxor1(c1); c1+=qxor2(c1);
        c2+=qxor1(c2); c2+=qxor2(c2);  c3+=qxor1(c3); c3+=qxor2(c3);
        c4+=qxor1(c4); c4+=qxor2(c4);  c5+=qxor1(c5); c5+=qxor2(c5);
        c6+=qxor1(c6); c6+=qxor2(c6);  c7+=qxor1(c7); c7+=qxor2(c7);
        ps+=qxor1(ps); ps+=qxor2(ps);
        // pack to f16 pairs for the 16-lane reduce (10 shuffles instead of 18)
        half2_t p01={(half_t)c0,(half_t)c1}, p23={(half_t)c2,(half_t)c3};
        half2_t p45={(half_t)c4,(half_t)c5}, p67={(half_t)c6,(half_t)c7};
        p01 = p01 + bcH(__shfl_xor(bcI(p01),4)); p23 = p23 + bcH(__shfl_xor(bcI(p23),4));
        p45 = p45 + bcH(__shfl_xor(bcI(p45),4)); p67 = p67 + bcH(__shfl_xor(bcI(p67),4));
        ps += __shfl_xor(ps,4);
        p01 = p01 + bcH(__shfl_xor(bcI(p01),8)); p23 = p23 + bcH(__shfl_xor(bcI(p23),8));
        p45 = p45 + bcH(__shfl_xor(bcI(p45),8)); p67 = p67 + bcH(__shfl_xor(bcI(p67),8));
        ps += __shfl_xor(ps,8);
        if (ts==0){
          float inv = rcp_f(ps);
          half2_t o01={(half_t)((float)p01[0]*inv),(half_t)((float)p01[1]*inv)};
          half2_t o23={(half_t)((float)p23[0]*inv),(half_t)((float)p23[1]*inv)};
          half2_t o45={(half_t)((float)p45[0]*inv),(half_t)((float)p45[1]*inv)};
          half2_t o67={(half_t)((float)p67[0]*inv),(half_t)((float)p67[1]*inv)};
          *reinterpret_cast<uint4*>(&sh_fc2in[l8][oc*8]) =
              make_uint4((unsigned)bcI(o01),(unsigned)bcI(o23),(unsigned)bcI(o45),(unsigned)bcI(o67));
        }
      }
      bar();
      // ==== P9: h_att[l] = fc2 @ [c|h_raw] + fc2_b (wE preloaded in P8) ====
      {
        float e0=0.f, e1=0.f;
        #pragma unroll
        for (int h=0; h<2; ++h){
          uint4 x0[4], x1[4];
          #pragma unroll
          for (int m=0;m<4;++m){
            x0[m] = *reinterpret_cast<const uint4*>(&sh_fc2in[0][64*q + 32*h + 8*m]);
            x1[m] = *reinterpret_cast<const uint4*>(&sh_fc2in[1][64*q + 32*h + 8*m]);
          }
          e0 += dot32(&wE[4*h],x0);
          e1 += dot32(&wE[4*h],x1);
        }
        e0 = qsum4(e0); e1 = qsum4(e1);
        __builtin_amdgcn_sched_barrier(0);
        // prefetch next step's Whh0 batch (everything else dead)
        #pragma unroll
        for (int n=0;n<3;++n)
          #pragma unroll
          for (int m=0;m<4;++m)
            wP1[4*n+m] = *reinterpret_cast<const uint4*>(W0 + ((size_t)(4*q+m)*384 + r + 128*n)*8);
        if      (q==0){ float v=e0+bF; sh_hatt32[0][r]=v; sh_hatt_pk[0][r]=(half_t)v; }
        else if (q==1){ float v=e1+bF; sh_hatt32[1][r]=v; sh_hatt_pk[1][r]=(half_t)v; }
      }
    } else {
      // prefetch next step's Whh0 batch
      #pragma unroll
      for (int n=0;n<3;++n)
        #pragma unroll
        for (int m=0;m<4;++m)
          wP1[4*n+m] = *reinterpret_cast<const uint4*>(W0 + ((size_t)(4*q+m)*384 + r + 128*n)*8);
      if (tid < 256){
        int l=tid>>7, row=tid&127;
        float hv = sh_hraw32[l][row];
        sh_hatt32[l][row]=hv; sh_hatt_pk[l][row]=(half_t)hv;
      }
    }
    bar();
  }
}

// Final: out[b,t] = sigmoid(tanh(out_W . [o1[b,t] | o2[b,min(t+10,127)]] + out_b))
__global__ void out_kernel(const half_t* __restrict__ o1h, const half_t* __restrict__ o2h,
                           const float* __restrict__ outW, const float* __restrict__ outb,
                           float* __restrict__ dout){
  int tid = blockIdx.x*blockDim.x + threadIdx.x;
  int q = tid&3, job = tid>>2;
  int b = job>>7, t = job&127;
  int t2 = t+10; if (t2>127) t2=127;
  const half_t* r1 = o1h + (size_t)(b*128+t)*128;
  const half_t* r2 = o2h + (size_t)(b*128+t2)*128;
  float acc=0.f;
  for (int j=q*32; j<q*32+32; ++j) acc += outW[j]*(float)r1[j];
  for (int j=q*32; j<q*32+32; ++j) acc += outW[128+j]*(float)r2[j];
  acc += __shfl_xor(acc,1);
  acc += __shfl_xor(acc,2);
  if (q==0){
    float d = tanhf_(acc + outb[0]);
    dout[job] = rcp_f(1.f+__expf(-d));
  }
}

static inline void launch_pack(const void* src, half_t* dst, int R, int K, int ld,
                               int coloff, int RT, int row_off, hipStream_t s){
  int total = R*K;
  pack_k<<<(total+255)/256, 256, 0, s>>>((const float*)src, dst, R, K, ld, coloff, RT, row_off);
}

extern "C" void kernel_launch(void* const* d_in, const int* in_sizes, int n_in,
                              void* d_out, int out_size, void* d_ws, size_t ws_size,
                              hipStream_t stream) {
  const float* received = (const float*)d_in[0];
  const float* Wih1_0 = (const float*)d_in[1];
  const float* Whh1_0 = (const float*)d_in[2];
  const float* bih1_0 = (const float*)d_in[3];
  const float* bhh1_0 = (const float*)d_in[4];
  const float* Wih1_1 = (const float*)d_in[5];
  const float* Whh1_1 = (const float*)d_in[6];
  const float* bih1_1 = (const float*)d_in[7];
  const float* bhh1_1 = (const float*)d_in[8];
  const float* Wih2_0 = (const float*)d_in[9];
  const float* Whh2_0 = (const float*)d_in[10];
  const float* bih2_0 = (const float*)d_in[11];
  const float* bhh2_0 = (const float*)d_in[12];
  const float* Wih2_1 = (const float*)d_in[13];
  const float* Whh2_1 = (const float*)d_in[14];
  const float* bih2_1 = (const float*)d_in[15];
  const float* bhh2_1 = (const float*)d_in[16];
  const float* attn_W = (const float*)d_in[17];
  const float* v_W    = (const float*)d_in[18];
  const float* fc2_W  = (const float*)d_in[19];
  const float* fc2_b  = (const float*)d_in[20];
  const float* out_W  = (const float*)d_in[21];
  const float* out_b  = (const float*)d_in[22];

  half_t* ws = (half_t*)d_ws;
  half_t* W0pack  = ws + 0;        // 2 x [16][384][8] = 98304
  half_t* W1pack  = ws + 98304;    // 2 x [16][768][8] = 196608
  half_t* WsPack  = ws + 294912;   // [16][128][8] = 16384
  half_t* WhPack  = ws + 311296;   // 16384
  half_t* fc2Pack = ws + 327552;   // [32][128][8] = 32768
  half_t* o1h     = ws + 360448;   // 32*128*128 = 524288
  half_t* o2h     = ws + 884736;   // 524288

  launch_pack(Whh1_0, W0pack,          384, 128, 128, 0, 384, 0, stream);
  launch_pack(Whh2_0, W0pack + 49152,  384, 128, 128, 0, 384, 0, stream);
  launch_pack(Wih1_1, W1pack,          384, 128, 128, 0, 768, 0, stream);
  launch_pack(Whh1_1, W1pack,          384, 128, 128, 0, 768, 384, stream);
  launch_pack(Wih2_1, W1pack + 98304,  384, 128, 128, 0, 768, 0, stream);
  launch_pack(Whh2_1, W1pack + 98304,  384, 128, 128, 0, 768, 384, stream);
  launch_pack(attn_W, WsPack,          128, 128, 256, 0,   128, 0, stream);
  launch_pack(attn_W, WhPack,          128, 128, 256, 128, 128, 0, stream);
  launch_pack(fc2_W,  fc2Pack,         128, 256, 256, 0,   128, 0, stream);

  gru_main<<<64, 512, 0, stream>>>(
      received,
      Wih1_0, Wih2_0,
      bih1_0, bhh1_0, bih1_1, bhh1_1,
      bih2_0, bhh2_0, bih2_1, bhh2_1,
      v_W, fc2_b,
      W0pack, W1pack, WsPack, WhPack, fc2Pack,
      o1h, o2h);

  out_kernel<<<64, 256, 0, stream>>>(o1h, o2h, out_W, out_b, (float*)d_out);
}